// Round 5
// baseline (1383.095 us; speedup 1.0000x reference)
//
#include <hip/hip_runtime.h>

// SeparableAttn: B=2, C=256, T=16, W=64, H=64.  All fp32 in/out.
// Cells: 0='T' (A=16,S=4096), 1='W' (A=64,S=1024), 2='H' (A=64,S=1024).
// Convs on MFMA (bf16 3-term split).  Applies register-tiled 4x4 fp32,
// single-barrier blocks (128 V-rows staged once), conflict-free attn reads.
// ws: qbuf 64M + kbuf 32M + vbuf 64M + Lp/attn + wfrag 1.5M + xTp 128M ~ 304MiB.

constexpr int XBS = 16777216; // per-batch x floats (256*16*64*64)

typedef __attribute__((ext_vector_type(8)))  short short8v;   // 8 bf16 = 4 VGPR
typedef __attribute__((ext_vector_type(16))) float f32x16;    // MFMA 32x32 acc

__device__ __forceinline__ unsigned rne16(float f) {
    unsigned u = __float_as_uint(f);
    return (u + 0x7FFFu + ((u >> 16) & 1u)) >> 16;   // bf16 RNE (finite vals)
}

// ---------------------------------------------------------------- prep_w
__global__ __launch_bounds__(64) void prep_w(
    const float* __restrict__ W, unsigned int* __restrict__ dst)
{
    const int l = threadIdx.x;
    const int ks = blockIdx.x, mf = blockIdx.y, hl = blockIdx.z;
    const float* src = W + (mf * 32 + (l & 31)) * 256 + ks * 16 + ((l >> 5) << 3);
    unsigned pk[4];
    #pragma unroll
    for (int e = 0; e < 4; ++e) {
        float f0 = src[2 * e], f1 = src[2 * e + 1];
        unsigned b0, b1;
        if (hl == 0) {
            b0 = __float_as_uint(f0) >> 16;
            b1 = __float_as_uint(f1) >> 16;
        } else {
            unsigned h0 = __float_as_uint(f0) & 0xFFFF0000u;
            unsigned h1 = __float_as_uint(f1) & 0xFFFF0000u;
            b0 = rne16(f0 - __uint_as_float(h0));
            b1 = rne16(f1 - __uint_as_float(h1));
        }
        pk[e] = b0 | (b1 << 16);
    }
    size_t off = ((size_t)(mf * 16 + ks) * 2 + hl) * 256 + l * 4;
    *(uint4*)&dst[off] = make_uint4(pk[0], pk[1], pk[2], pk[3]);
}

// ---------------------------------------------------------------- xsplit
// xTp[b][n][c] (packed hi16|lo16) = split(x_perm[c][n]).
template<int CELL>
__global__ __launch_bounds__(256) void xsplit_kernel(
    const float* __restrict__ src, unsigned int* __restrict__ xTp)
{
    __shared__ float T[64][66];   // [c][run], pad 66
    const int tid = threadIdx.x;
    const int b = blockIdx.z, cb = blockIdx.y, nb = blockIdx.x;
    const int runbase = (CELL == 0) ? nb * 64
                                    : ((nb & 15) * 4096 + ((nb >> 4) << 6));
    const float* sp = src + (size_t)b * XBS + (size_t)(cb * 64) * 65536 + runbase;
    #pragma unroll
    for (int i = 0; i < 4; ++i) {
        int id = tid + i * 256;
        int cl = id >> 4, rc = (id & 15) * 4;
        const float4 v = *(const float4*)&sp[(size_t)cl * 65536 + rc];
        *(float2*)&T[cl][rc]     = make_float2(v.x, v.y);
        *(float2*)&T[cl][rc + 2] = make_float2(v.z, v.w);
    }
    __syncthreads();
    unsigned int* dst = xTp + (size_t)b * (65536u * 256u);
    #pragma unroll
    for (int ps = 0; ps < 4; ++ps) {
        int r = ps * 16 + (tid >> 4);       // run index
        int c0 = (tid & 15) * 4;
        unsigned pk[4];
        #pragma unroll
        for (int e = 0; e < 4; ++e) {
            float f = T[c0 + e][r];
            unsigned hi = __float_as_uint(f) & 0xFFFF0000u;
            pk[e] = hi | rne16(f - __uint_as_float(hi));
        }
        int n_row = (CELL == 2) ? (r * 1024 + nb) : (nb * 64 + r);
        *(uint4*)&dst[(size_t)n_row * 256 + cb * 64 + c0] =
            make_uint4(pk[0], pk[1], pk[2], pk[3]);
    }
}

// ---------------------------------------------------------------- mconv
// (unchanged, verified)
template<bool POOL, int LGS>
__global__ __launch_bounds__(256, 2) void mconv(
    const unsigned int* __restrict__ xTp, const unsigned int* __restrict__ wf,
    const float* __restrict__ bias, float* __restrict__ out, int obs)
{
    constexpr int NS = POOL ? 32768 : 65536;
    constexpr int MF = POOL ? 2 : 4;
    constexpr int NV = POOL ? 2 : 1;

    __shared__ __align__(16) unsigned short Bh[128 * 64];
    __shared__ __align__(16) unsigned short Bl[128 * 64];

    const int tid = threadIdx.x;
    const int lane = tid & 63, wv = tid >> 6;
    const int b = blockIdx.z, gy = blockIdx.y, nb = blockIdx.x;
    const unsigned int* xb = xTp + (size_t)b * (65536u * 256u);

    f32x16 acc[MF][NV];
    #pragma unroll
    for (int m = 0; m < MF; ++m)
        #pragma unroll
        for (int v = 0; v < NV; ++v)
            #pragma unroll
            for (int r = 0; r < 16; ++r) acc[m][v][r] = 0.f;

    for (int ko = 0; ko < 4; ++ko) {
        const int c0u = ko * 64;
        #pragma unroll
        for (int i = 0; i < 8; ++i) {
            int id = tid + i * 256;
            int row = id >> 4, q4 = id & 15;
            int n_src;
            if (!POOL) n_src = nb * 128 + row;
            else {
                int v = row >> 6, m = nb * 64 + (row & 63);
                int p = m >> LGS, s = m & ((1 << LGS) - 1);
                n_src = ((2 * p + v) << LGS) + s;
            }
            const uint4 g = *(const uint4*)&xb[(size_t)n_src * 256 + c0u + q4 * 4];
            unsigned h01 = (g.x >> 16)     | (g.y & 0xFFFF0000u);
            unsigned h23 = (g.z >> 16)     | (g.w & 0xFFFF0000u);
            unsigned l01 = (g.x & 0xFFFFu) | (g.y << 16);
            unsigned l23 = (g.z & 0xFFFFu) | (g.w << 16);
            int byt = row * 128 + (((q4 >> 1) ^ (row & 7)) << 4) + ((q4 & 1) << 3);
            *(uint2*)((char*)Bh + byt) = make_uint2(h01, h23);
            *(uint2*)((char*)Bl + byt) = make_uint2(l01, l23);
        }
        __syncthreads();
        #pragma unroll
        for (int ks = 0; ks < 4; ++ks) {
            short8v ah[MF], al[MF];
            #pragma unroll
            for (int m = 0; m < MF; ++m) {
                int mfG = gy * 4 + (POOL ? ((wv >> 1) * 2 + m) : m);
                const unsigned int* ap =
                    wf + (size_t)((mfG * 16 + ko * 4 + ks) * 2) * 256 + lane * 4;
                ah[m] = *(const short8v*)ap;
                al[m] = *(const short8v*)(ap + 256);
            }
            #pragma unroll
            for (int v = 0; v < NV; ++v) {
                int row = POOL ? (v * 64 + (wv & 1) * 32 + (lane & 31))
                               : (wv * 32 + (lane & 31));
                int byt = row * 128 + (((ks * 2 + (lane >> 5)) ^ (row & 7)) << 4);
                short8v bh = *(const short8v*)((char*)Bh + byt);
                short8v bl = *(const short8v*)((char*)Bl + byt);
                #pragma unroll
                for (int m = 0; m < MF; ++m) {
                    acc[m][v] = __builtin_amdgcn_mfma_f32_32x32x16_bf16(ah[m], bh, acc[m][v], 0, 0, 0);
                    acc[m][v] = __builtin_amdgcn_mfma_f32_32x32x16_bf16(ah[m], bl, acc[m][v], 0, 0, 0);
                    acc[m][v] = __builtin_amdgcn_mfma_f32_32x32x16_bf16(al[m], bh, acc[m][v], 0, 0, 0);
                }
            }
        }
        __syncthreads();
    }

    float* ob = out + (size_t)b * obs;
    const int colbase = POOL ? (nb * 64 + (wv & 1) * 32 + (lane & 31))
                             : (nb * 128 + wv * 32 + (lane & 31));
    #pragma unroll
    for (int m = 0; m < MF; ++m) {
        int mfG = gy * 4 + (POOL ? ((wv >> 1) * 2 + m) : m);
        #pragma unroll
        for (int r = 0; r < 16; ++r) {
            int o = mfG * 32 + (r & 3) + 8 * (r >> 2) + 4 * (lane >> 5);
            float val = POOL ? fmaxf(acc[m][0][r], acc[m][1][r]) : acc[m][0][r];
            ob[(size_t)o * NS + colbase] = val + bias[o];
        }
    }
}

// ---------------------------------------------------------------- logits
template<int A, int AH, int PP, int G, int KS, int M>
__global__ __launch_bounds__(256) void logits_kernel(
    const float* __restrict__ qb, const float* __restrict__ kb,
    float* __restrict__ Lpart)
{
    const int tid = threadIdx.x;
    const int jl = tid & 63, pg = tid >> 6;
    const int p0 = pg * PP;
    const int b = blockIdx.z, a0 = blockIdx.y * G, kc = blockIdx.x;
    constexpr int CH = M / KS;
    const float* q = qb + (size_t)b * 8388608 + (size_t)a0 * M + (size_t)kc * CH;
    const float* k = kb + (size_t)b * 4194304;

    float acc[G][PP];
    #pragma unroll
    for (int g = 0; g < G; ++g)
        #pragma unroll
        for (int pp = 0; pp < PP; ++pp) acc[g][pp] = 0.f;

    for (int it = 0; it < CH / 64; ++it) {
        const int jo = jl + it * 64;
        const int j  = kc * CH + jo;
        float qv[G];
        #pragma unroll
        for (int g = 0; g < G; ++g) qv[g] = q[g * M + jo];
        float kv[PP];
        if (PP == 8) {
            float4 k0 = *(const float4*)&k[(size_t)j * AH + p0];
            float4 k1 = *(const float4*)&k[(size_t)j * AH + p0 + 4];
            kv[0]=k0.x; kv[1]=k0.y; kv[2]=k0.z; kv[3]=k0.w;
            kv[4]=k1.x; kv[5]=k1.y; kv[6]=k1.z; kv[7]=k1.w;
        } else {
            float2 k0 = *(const float2*)&k[(size_t)j * AH + p0];
            kv[0]=k0.x; if (PP > 1) kv[1]=k0.y;
        }
        #pragma unroll
        for (int g = 0; g < G; ++g)
            #pragma unroll
            for (int pp = 0; pp < PP; ++pp) acc[g][pp] += qv[g] * kv[pp];
    }

    #pragma unroll
    for (int g = 0; g < G; ++g)
        #pragma unroll
        for (int pp = 0; pp < PP; ++pp) {
            float v = acc[g][pp];
            #pragma unroll
            for (int off = 32; off; off >>= 1) v += __shfl_down(v, off, 64);
            if (jl == 0)
                Lpart[(size_t)(((b * A + a0 + g) * AH) + p0 + pp) * KS + kc] = v;
        }
}

// ---------------------------------------------------------------- softmax
__global__ __launch_bounds__(64) void softmax_kernel(
    const float* __restrict__ Lpart, float* __restrict__ attn,
    int AH, int KS)
{
    const int row = blockIdx.x;
    const int p = threadIdx.x;
    float s = 0.f;
    if (p < AH) {
        const size_t base = (size_t)(row * AH + p) * KS;
        for (int kc = 0; kc < KS; ++kc) s += Lpart[base + kc];
    }
    float m = (p < AH) ? s : -3.4e38f;
    #pragma unroll
    for (int off = 32; off; off >>= 1) m = fmaxf(m, __shfl_xor(m, off, 64));
    float e = (p < AH) ? __expf(s - m) : 0.f;
    float t = e;
    #pragma unroll
    for (int off = 32; off; off >>= 1) t += __shfl_xor(t, off, 64);
    if (p < AH) attn[(size_t)row * AH + p] = e / t;
}

// ---------------------------------------------------------------- apply
// o[b,x,a] = sum_p V[x,p]*attn[a,p];  xdst = gamma*o(un-permuted) + xsrc.
// CELL 1/2: block = 128 consecutive V-rows x all 64 a; V staged ONCE (16KB),
// attnA staged ONCE -> single __syncthreads per block.  Thread tile 4r x 4a.
// attnA stride 32, chunk XOR (ch ^ ((a>>2)&7)): per-wave a-groups are
// consecutive g -> 4 distinct slot-quads -> conflict-free reads.
// vls stride 32, chunk XOR (ch ^ ((r>>2)&7)): residual 2-way (k vs k+8).
// CELL 0 unchanged (direct-global V, verified).
// In-place safe: each elem read+written by the same thread.
template<int CELL>
__global__ __launch_bounds__(256) void apply_kernel(
    const float* __restrict__ vbuf, const float* __restrict__ attn,
    const float* __restrict__ xsrc, float* __restrict__ xdst,
    const float* __restrict__ gp, int gidx)
{
    constexpr int A  = (CELL == 0) ? 16 : 64;
    constexpr int AH = A / 2;            // 8 / 32

    __shared__ float attnA[(CELL == 0) ? 16 * 12 : 64 * 32];
    __shared__ float vls[(CELL == 0) ? 4 : 128 * 32];     // 16KB (cells 1/2)

    const int tid = threadIdx.x;
    const int b = blockIdx.z, c = blockIdx.y;

    const float g = gp[gidx];
    const float* xs = xsrc + (size_t)b * XBS + (size_t)c * 65536;
    float*       xd = xdst + (size_t)b * XBS + (size_t)c * 65536;
    const float* vb = vbuf + (size_t)b * 8388608;

    if (CELL == 0) {
        // stage attnA [a][p] padded stride 12
        for (int idx = tid; idx < A * AH / 4; idx += 256) {
            int a = idx / 2, q = idx % 2;
            *(float4*)&attnA[a * 12 + q * 4] =
                *(const float4*)&attn[(size_t)b * A * AH + a * AH + q * 4];
        }
        __syncthreads();
        const int i0 = blockIdx.x * 8;
        const int r0 = (tid & 63) * 4;
        const int il = r0 >> 6, j0 = r0 & 63;
        const int a0 = (tid >> 6) * 4;
        float4 aa[2][4];
        #pragma unroll
        for (int ch = 0; ch < 2; ++ch)
            #pragma unroll
            for (int at = 0; at < 4; ++at)
                aa[ch][at] = *(const float4*)&attnA[(a0 + at) * 12 + ch * 4];
        for (int ig = 0; ig < 2; ++ig) {
            const int i = i0 + ig * 4 + il;
            const float* vrow = vb + ((size_t)(c * 64 + i) * 64 + j0) * 8;
            float acc[4][4];
            #pragma unroll
            for (int rt = 0; rt < 4; ++rt)
                #pragma unroll
                for (int at = 0; at < 4; ++at) acc[rt][at] = 0.f;
            #pragma unroll
            for (int ch = 0; ch < 2; ++ch)
                #pragma unroll
                for (int rt = 0; rt < 4; ++rt) {
                    float4 vv = *(const float4*)&vrow[rt * 8 + ch * 4];
                    #pragma unroll
                    for (int at = 0; at < 4; ++at)
                        acc[rt][at] += vv.x * aa[ch][at].x + vv.y * aa[ch][at].y
                                     + vv.z * aa[ch][at].z + vv.w * aa[ch][at].w;
                }
            #pragma unroll
            for (int at = 0; at < 4; ++at) {
                int a = a0 + at;
                size_t xi = (size_t)a * 4096 + i * 64 + j0;
                float4 sv = *(const float4*)&xs[xi];
                *(float4*)&xd[xi] = make_float4(
                    g * acc[0][at] + sv.x, g * acc[1][at] + sv.y,
                    g * acc[2][at] + sv.z, g * acc[3][at] + sv.w);
            }
        }
    } else {
        // rows RB..RB+128 of vbuf; cell1: i0=bx*2 (2 i's), cell2: i0=bx*8 (8 i's)
        const int i0 = blockIdx.x * ((CELL == 1) ? 2 : 8);
        const int RB = c * 1024 + i0 * ((CELL == 1) ? 64 : 16);

        // stage attnA: [a*32 + (ch^((a>>2)&7))*4], 512 f4, coalesced reads
        #pragma unroll
        for (int u = 0; u < 2; ++u) {
            int idx = tid + u * 256;
            int a = idx >> 3, ch = idx & 7;
            *(float4*)&attnA[a * 32 + ((ch ^ ((a >> 2) & 7)) << 2)] =
                *(const float4*)&attn[(size_t)b * 2048 + a * 32 + ch * 4];
        }
        // stage vls: 128 rows x 8 chunks, [r*32 + (cc^((r>>2)&7))*4]
        #pragma unroll
        for (int t = 0; t < 4; ++t) {
            int idx = tid + t * 256;
            int r = idx >> 3, cc = idx & 7;
            *(float4*)&vls[r * 32 + ((cc ^ ((r >> 2) & 7)) << 2)] =
                *(const float4*)&vb[(size_t)(RB + r) * 32 + cc * 4];
        }
        __syncthreads();

        const int k = tid & 15, gg = tid >> 4;
        const int a0 = gg * 4;
        #pragma unroll
        for (int ph = 0; ph < 2; ++ph) {
            const int r0 = ph * 64 + k * 4;
            float acc[4][4];
            #pragma unroll
            for (int rt = 0; rt < 4; ++rt)
                #pragma unroll
                for (int at = 0; at < 4; ++at) acc[rt][at] = 0.f;
            #pragma unroll
            for (int ch = 0; ch < 8; ++ch) {
                const int slotA = (ch ^ (gg & 7)) << 2;
                const int slotV = (ch ^ (k & 7)) << 2;
                float4 aa[4];
                #pragma unroll
                for (int at = 0; at < 4; ++at)
                    aa[at] = *(const float4*)&attnA[(a0 + at) * 32 + slotA];
                #pragma unroll
                for (int rt = 0; rt < 4; ++rt) {
                    float4 vv = *(const float4*)&vls[(r0 + rt) * 32 + slotV];
                    #pragma unroll
                    for (int at = 0; at < 4; ++at)
                        acc[rt][at] += vv.x * aa[at].x + vv.y * aa[at].y
                                     + vv.z * aa[at].z + vv.w * aa[at].w;
                }
            }
            if (CELL == 1) {
                const int i = i0 + ph, j0 = k * 4;
                #pragma unroll
                for (int at = 0; at < 4; ++at) {
                    int a = a0 + at;
                    size_t xi = (size_t)i * 4096 + a * 64 + j0;
                    float4 sv = *(const float4*)&xs[xi];
                    *(float4*)&xd[xi] = make_float4(
                        g * acc[0][at] + sv.x, g * acc[1][at] + sv.y,
                        g * acc[2][at] + sv.z, g * acc[3][at] + sv.w);
                }
            } else {
                #pragma unroll
                for (int rt = 0; rt < 4; ++rt) {
                    int rl = k * 4 + rt;                  // 0..63 within pass
                    int i = i0 + ph * 4 + (rl >> 4), j = rl & 15;
                    size_t xi = (size_t)i * 1024 + j * 64 + a0;
                    float4 sv = *(const float4*)&xs[xi];
                    *(float4*)&xd[xi] = make_float4(
                        g * acc[rt][0] + sv.x, g * acc[rt][1] + sv.y,
                        g * acc[rt][2] + sv.z, g * acc[rt][3] + sv.w);
                }
            }
        }
    }
}

// ---------------------------------------------------------------- launch
extern "C" void kernel_launch(void* const* d_in, const int* in_sizes, int n_in,
                              void* d_out, int out_size, void* d_ws, size_t ws_size,
                              hipStream_t stream)
{
    const float* x  = (const float*)d_in[0];
    const float* Wq = (const float*)d_in[1];
    const float* bq = (const float*)d_in[2];
    const float* Wk = (const float*)d_in[3];
    const float* bk = (const float*)d_in[4];
    const float* Wv = (const float*)d_in[5];
    const float* bv = (const float*)d_in[6];
    const float* gm = (const float*)d_in[7];
    float* out = (float*)d_out;

    float* ws   = (float*)d_ws;
    float* qbuf = ws;                      // 16777216 f
    float* kbuf = qbuf + 16777216;         //  8388608 f
    float* vbuf = kbuf + 8388608;          // 16777216 f
    float* Lp   = vbuf + 16777216;         //    65536 f
    float* attn = Lp + 65536;              //     4096 f
    unsigned int* wfb = (unsigned int*)(attn + 4096);   // 3*131072 u32 (1.5MiB)
    unsigned int* xTp = wfb + 3 * 131072;               // 33554432 u32 (128MiB)

    dim3 B256(256), B64(64);

    // weight prep (frag-ordered bf16 hi/lo) — data-independent, once up front
    for (int c = 0; c < 3; ++c) {
        unsigned int* wfc = wfb + c * 131072;
        prep_w<<<dim3(16,4,2),B64,0,stream>>>(Wq + c*32768, wfc);
        prep_w<<<dim3(16,4,2),B64,0,stream>>>(Wk + c*32768, wfc + 32768);
        prep_w<<<dim3(16,8,2),B64,0,stream>>>(Wv + c*65536, wfc + 65536);
    }

    // ---- cell 0: 'T' ----
    xsplit_kernel<0><<<dim3(1024,4,2),B256,0,stream>>>(x, xTp);
    mconv<false,12><<<dim3(512,1,2),B256,0,stream>>>(xTp, wfb,          bq, qbuf, 8388608);
    mconv<true ,12><<<dim3(512,1,2),B256,0,stream>>>(xTp, wfb + 32768,  bk, kbuf, 4194304);
    mconv<true ,12><<<dim3(512,2,2),B256,0,stream>>>(xTp, wfb + 65536,  bv, vbuf, 8388608);
    logits_kernel<16,8,2,8,64,524288><<<dim3(64,2,2),B256,0,stream>>>(qbuf, kbuf, Lp);
    softmax_kernel<<<dim3(32),B64,0,stream>>>(Lp, attn, 8, 64);
    apply_kernel<0><<<dim3(8,256,2),B256,0,stream>>>(vbuf, attn, x, out, gm, 0);

    // ---- cell 1: 'W' ----
    unsigned int* wf1 = wfb + 131072;
    xsplit_kernel<1><<<dim3(1024,4,2),B256,0,stream>>>(out, xTp);
    mconv<false,10><<<dim3(512,1,2),B256,0,stream>>>(xTp, wf1,          bq+128, qbuf, 8388608);
    mconv<true ,10><<<dim3(512,1,2),B256,0,stream>>>(xTp, wf1 + 32768,  bk+128, kbuf, 4194304);
    mconv<true ,10><<<dim3(512,2,2),B256,0,stream>>>(xTp, wf1 + 65536,  bv+256, vbuf, 8388608);
    logits_kernel<64,32,8,8,16,131072><<<dim3(16,8,2),B256,0,stream>>>(qbuf, kbuf, Lp);
    softmax_kernel<<<dim3(128),B64,0,stream>>>(Lp, attn, 32, 16);
    apply_kernel<1><<<dim3(8,256,2),B256,0,stream>>>(vbuf, attn, out, out, gm, 1);

    // ---- cell 2: 'H' ----
    unsigned int* wf2 = wfb + 262144;
    xsplit_kernel<2><<<dim3(1024,4,2),B256,0,stream>>>(out, xTp);
    mconv<false,10><<<dim3(512,1,2),B256,0,stream>>>(xTp, wf2,          bq+256, qbuf, 8388608);
    mconv<true ,10><<<dim3(512,1,2),B256,0,stream>>>(xTp, wf2 + 32768,  bk+256, kbuf, 4194304);
    mconv<true ,10><<<dim3(512,2,2),B256,0,stream>>>(xTp, wf2 + 65536,  bv+512, vbuf, 8388608);
    logits_kernel<64,32,8,8,16,131072><<<dim3(16,8,2),B256,0,stream>>>(qbuf, kbuf, Lp);
    softmax_kernel<<<dim3(128),B64,0,stream>>>(Lp, attn, 32, 16);
    apply_kernel<2><<<dim3(8,256,2),B256,0,stream>>>(vbuf, attn, out, out, gm, 2);
}

// Round 6
// 1231.193 us; speedup vs baseline: 1.1234x; 1.1234x over previous
//
#include <hip/hip_runtime.h>

// SeparableAttn: B=2, C=256, T=16, W=64, H=64.  All fp32 in/out.
// Cells: 0='T' (A=16,S=4096), 1='W' (A=64,S=1024), 2='H' (A=64,S=1024).
// Convs on MFMA (bf16 3-term split).  Applies register-tiled 4x4 fp32
// (round-4 verified structure).  V-conv retiled: 32 cols x 256 o per block
// (xTp read once, staging halved).  Cell-0 logits split-K doubled.
// ws: qbuf 64M + kbuf 32M + vbuf 64M + Lp/attn + wfrag 1.5M + xTp 128M ~ 304MiB.

constexpr int XBS = 16777216; // per-batch x floats (256*16*64*64)

typedef __attribute__((ext_vector_type(8)))  short short8v;   // 8 bf16 = 4 VGPR
typedef __attribute__((ext_vector_type(16))) float f32x16;    // MFMA 32x32 acc

__device__ __forceinline__ unsigned rne16(float f) {
    unsigned u = __float_as_uint(f);
    return (u + 0x7FFFu + ((u >> 16) & 1u)) >> 16;   // bf16 RNE (finite vals)
}

// ---------------------------------------------------------------- prep_w
__global__ __launch_bounds__(64) void prep_w(
    const float* __restrict__ W, unsigned int* __restrict__ dst)
{
    const int l = threadIdx.x;
    const int ks = blockIdx.x, mf = blockIdx.y, hl = blockIdx.z;
    const float* src = W + (mf * 32 + (l & 31)) * 256 + ks * 16 + ((l >> 5) << 3);
    unsigned pk[4];
    #pragma unroll
    for (int e = 0; e < 4; ++e) {
        float f0 = src[2 * e], f1 = src[2 * e + 1];
        unsigned b0, b1;
        if (hl == 0) {
            b0 = __float_as_uint(f0) >> 16;
            b1 = __float_as_uint(f1) >> 16;
        } else {
            unsigned h0 = __float_as_uint(f0) & 0xFFFF0000u;
            unsigned h1 = __float_as_uint(f1) & 0xFFFF0000u;
            b0 = rne16(f0 - __uint_as_float(h0));
            b1 = rne16(f1 - __uint_as_float(h1));
        }
        pk[e] = b0 | (b1 << 16);
    }
    size_t off = ((size_t)(mf * 16 + ks) * 2 + hl) * 256 + l * 4;
    *(uint4*)&dst[off] = make_uint4(pk[0], pk[1], pk[2], pk[3]);
}

// ---------------------------------------------------------------- xsplit
// xTp[b][n][c] (packed hi16|lo16) = split(x_perm[c][n]).
template<int CELL>
__global__ __launch_bounds__(256) void xsplit_kernel(
    const float* __restrict__ src, unsigned int* __restrict__ xTp)
{
    __shared__ float T[64][66];   // [c][run], pad 66
    const int tid = threadIdx.x;
    const int b = blockIdx.z, cb = blockIdx.y, nb = blockIdx.x;
    const int runbase = (CELL == 0) ? nb * 64
                                    : ((nb & 15) * 4096 + ((nb >> 4) << 6));
    const float* sp = src + (size_t)b * XBS + (size_t)(cb * 64) * 65536 + runbase;
    #pragma unroll
    for (int i = 0; i < 4; ++i) {
        int id = tid + i * 256;
        int cl = id >> 4, rc = (id & 15) * 4;
        const float4 v = *(const float4*)&sp[(size_t)cl * 65536 + rc];
        *(float2*)&T[cl][rc]     = make_float2(v.x, v.y);
        *(float2*)&T[cl][rc + 2] = make_float2(v.z, v.w);
    }
    __syncthreads();
    unsigned int* dst = xTp + (size_t)b * (65536u * 256u);
    #pragma unroll
    for (int ps = 0; ps < 4; ++ps) {
        int r = ps * 16 + (tid >> 4);       // run index
        int c0 = (tid & 15) * 4;
        unsigned pk[4];
        #pragma unroll
        for (int e = 0; e < 4; ++e) {
            float f = T[c0 + e][r];
            unsigned hi = __float_as_uint(f) & 0xFFFF0000u;
            pk[e] = hi | rne16(f - __uint_as_float(hi));
        }
        int n_row = (CELL == 2) ? (r * 1024 + nb) : (nb * 64 + r);
        *(uint4*)&dst[(size_t)n_row * 256 + cb * 64 + c0] =
            make_uint4(pk[0], pk[1], pk[2], pk[3]);
    }
}

// ---------------------------------------------------------------- mconv
// (unchanged, verified) — used for Q (non-pool) and K (pool, gy=0).
template<bool POOL, int LGS>
__global__ __launch_bounds__(256, 2) void mconv(
    const unsigned int* __restrict__ xTp, const unsigned int* __restrict__ wf,
    const float* __restrict__ bias, float* __restrict__ out, int obs)
{
    constexpr int NS = POOL ? 32768 : 65536;
    constexpr int MF = POOL ? 2 : 4;
    constexpr int NV = POOL ? 2 : 1;

    __shared__ __align__(16) unsigned short Bh[128 * 64];
    __shared__ __align__(16) unsigned short Bl[128 * 64];

    const int tid = threadIdx.x;
    const int lane = tid & 63, wv = tid >> 6;
    const int b = blockIdx.z, gy = blockIdx.y, nb = blockIdx.x;
    const unsigned int* xb = xTp + (size_t)b * (65536u * 256u);

    f32x16 acc[MF][NV];
    #pragma unroll
    for (int m = 0; m < MF; ++m)
        #pragma unroll
        for (int v = 0; v < NV; ++v)
            #pragma unroll
            for (int r = 0; r < 16; ++r) acc[m][v][r] = 0.f;

    for (int ko = 0; ko < 4; ++ko) {
        const int c0u = ko * 64;
        #pragma unroll
        for (int i = 0; i < 8; ++i) {
            int id = tid + i * 256;
            int row = id >> 4, q4 = id & 15;
            int n_src;
            if (!POOL) n_src = nb * 128 + row;
            else {
                int v = row >> 6, m = nb * 64 + (row & 63);
                int p = m >> LGS, s = m & ((1 << LGS) - 1);
                n_src = ((2 * p + v) << LGS) + s;
            }
            const uint4 g = *(const uint4*)&xb[(size_t)n_src * 256 + c0u + q4 * 4];
            unsigned h01 = (g.x >> 16)     | (g.y & 0xFFFF0000u);
            unsigned h23 = (g.z >> 16)     | (g.w & 0xFFFF0000u);
            unsigned l01 = (g.x & 0xFFFFu) | (g.y << 16);
            unsigned l23 = (g.z & 0xFFFFu) | (g.w << 16);
            int byt = row * 128 + (((q4 >> 1) ^ (row & 7)) << 4) + ((q4 & 1) << 3);
            *(uint2*)((char*)Bh + byt) = make_uint2(h01, h23);
            *(uint2*)((char*)Bl + byt) = make_uint2(l01, l23);
        }
        __syncthreads();
        #pragma unroll
        for (int ks = 0; ks < 4; ++ks) {
            short8v ah[MF], al[MF];
            #pragma unroll
            for (int m = 0; m < MF; ++m) {
                int mfG = gy * 4 + (POOL ? ((wv >> 1) * 2 + m) : m);
                const unsigned int* ap =
                    wf + (size_t)((mfG * 16 + ko * 4 + ks) * 2) * 256 + lane * 4;
                ah[m] = *(const short8v*)ap;
                al[m] = *(const short8v*)(ap + 256);
            }
            #pragma unroll
            for (int v = 0; v < NV; ++v) {
                int row = POOL ? (v * 64 + (wv & 1) * 32 + (lane & 31))
                               : (wv * 32 + (lane & 31));
                int byt = row * 128 + (((ks * 2 + (lane >> 5)) ^ (row & 7)) << 4);
                short8v bh = *(const short8v*)((char*)Bh + byt);
                short8v bl = *(const short8v*)((char*)Bl + byt);
                #pragma unroll
                for (int m = 0; m < MF; ++m) {
                    acc[m][v] = __builtin_amdgcn_mfma_f32_32x32x16_bf16(ah[m], bh, acc[m][v], 0, 0, 0);
                    acc[m][v] = __builtin_amdgcn_mfma_f32_32x32x16_bf16(ah[m], bl, acc[m][v], 0, 0, 0);
                    acc[m][v] = __builtin_amdgcn_mfma_f32_32x32x16_bf16(al[m], bh, acc[m][v], 0, 0, 0);
                }
            }
        }
        __syncthreads();
    }

    float* ob = out + (size_t)b * obs;
    const int colbase = POOL ? (nb * 64 + (wv & 1) * 32 + (lane & 31))
                             : (nb * 128 + wv * 32 + (lane & 31));
    #pragma unroll
    for (int m = 0; m < MF; ++m) {
        int mfG = gy * 4 + (POOL ? ((wv >> 1) * 2 + m) : m);
        #pragma unroll
        for (int r = 0; r < 16; ++r) {
            int o = mfG * 32 + (r & 3) + 8 * (r >> 2) + 4 * (lane >> 5);
            float val = POOL ? fmaxf(acc[m][0][r], acc[m][1][r]) : acc[m][0][r];
            ob[(size_t)o * NS + colbase] = val + bias[o];
        }
    }
}

// ---------------------------------------------------------------- mconv_v
// V conv: 32 pooled cols x 256 o per block (waves = o-quarters, both pool
// variants in-wave).  xTp rows read ONCE (old gy=2 read them twice);
// staging bytes/VALU halved.  acc 2x2x16 = 64 regs (same as mconv-pool).
template<int LGS>
__global__ __launch_bounds__(256, 2) void mconv_v(
    const unsigned int* __restrict__ xTp, const unsigned int* __restrict__ wf,
    const float* __restrict__ bias, float* __restrict__ out)
{
    __shared__ __align__(16) unsigned short Bh[64 * 64];
    __shared__ __align__(16) unsigned short Bl[64 * 64];

    const int tid = threadIdx.x;
    const int lane = tid & 63, wv = tid >> 6;
    const int b = blockIdx.z, nb = blockIdx.x;
    const unsigned int* xb = xTp + (size_t)b * (65536u * 256u);

    f32x16 acc[2][2];
    #pragma unroll
    for (int m = 0; m < 2; ++m)
        #pragma unroll
        for (int v = 0; v < 2; ++v)
            #pragma unroll
            for (int r = 0; r < 16; ++r) acc[m][v][r] = 0.f;

    for (int ko = 0; ko < 4; ++ko) {
        const int c0u = ko * 64;
        #pragma unroll
        for (int i = 0; i < 4; ++i) {
            int id = tid + i * 256;
            int row = id >> 4, q4 = id & 15;       // row 0..63
            int v = row >> 5, m = nb * 32 + (row & 31);
            int p = m >> LGS, s = m & ((1 << LGS) - 1);
            int n_src = ((2 * p + v) << LGS) + s;
            const uint4 g = *(const uint4*)&xb[(size_t)n_src * 256 + c0u + q4 * 4];
            unsigned h01 = (g.x >> 16)     | (g.y & 0xFFFF0000u);
            unsigned h23 = (g.z >> 16)     | (g.w & 0xFFFF0000u);
            unsigned l01 = (g.x & 0xFFFFu) | (g.y << 16);
            unsigned l23 = (g.z & 0xFFFFu) | (g.w << 16);
            int byt = row * 128 + (((q4 >> 1) ^ (row & 7)) << 4) + ((q4 & 1) << 3);
            *(uint2*)((char*)Bh + byt) = make_uint2(h01, h23);
            *(uint2*)((char*)Bl + byt) = make_uint2(l01, l23);
        }
        __syncthreads();
        #pragma unroll
        for (int ks = 0; ks < 4; ++ks) {
            short8v ah[2], al[2];
            #pragma unroll
            for (int m = 0; m < 2; ++m) {
                int mfG = wv * 2 + m;               // 0..7 -> 256 o
                const unsigned int* ap =
                    wf + (size_t)((mfG * 16 + ko * 4 + ks) * 2) * 256 + lane * 4;
                ah[m] = *(const short8v*)ap;
                al[m] = *(const short8v*)(ap + 256);
            }
            #pragma unroll
            for (int v = 0; v < 2; ++v) {
                int row = v * 32 + (lane & 31);
                int byt = row * 128 + (((ks * 2 + (lane >> 5)) ^ (row & 7)) << 4);
                short8v bh = *(const short8v*)((char*)Bh + byt);
                short8v bl = *(const short8v*)((char*)Bl + byt);
                #pragma unroll
                for (int m = 0; m < 2; ++m) {
                    acc[m][v] = __builtin_amdgcn_mfma_f32_32x32x16_bf16(ah[m], bh, acc[m][v], 0, 0, 0);
                    acc[m][v] = __builtin_amdgcn_mfma_f32_32x32x16_bf16(ah[m], bl, acc[m][v], 0, 0, 0);
                    acc[m][v] = __builtin_amdgcn_mfma_f32_32x32x16_bf16(al[m], bh, acc[m][v], 0, 0, 0);
                }
            }
        }
        __syncthreads();
    }

    float* ob = out + (size_t)b * 8388608;
    const int colbase = nb * 32 + (lane & 31);
    #pragma unroll
    for (int m = 0; m < 2; ++m) {
        int mfG = wv * 2 + m;
        #pragma unroll
        for (int r = 0; r < 16; ++r) {
            int o = mfG * 32 + (r & 3) + 8 * (r >> 2) + 4 * (lane >> 5);
            float val = fmaxf(acc[m][0][r], acc[m][1][r]);
            ob[(size_t)o * 32768 + colbase] = val + bias[o];
        }
    }
}

// ---------------------------------------------------------------- logits
template<int A, int AH, int PP, int G, int KS, int M>
__global__ __launch_bounds__(256) void logits_kernel(
    const float* __restrict__ qb, const float* __restrict__ kb,
    float* __restrict__ Lpart)
{
    const int tid = threadIdx.x;
    const int jl = tid & 63, pg = tid >> 6;
    const int p0 = pg * PP;
    const int b = blockIdx.z, a0 = blockIdx.y * G, kc = blockIdx.x;
    constexpr int CH = M / KS;
    const float* q = qb + (size_t)b * 8388608 + (size_t)a0 * M + (size_t)kc * CH;
    const float* k = kb + (size_t)b * 4194304;

    float acc[G][PP];
    #pragma unroll
    for (int g = 0; g < G; ++g)
        #pragma unroll
        for (int pp = 0; pp < PP; ++pp) acc[g][pp] = 0.f;

    for (int it = 0; it < CH / 64; ++it) {
        const int jo = jl + it * 64;
        const int j  = kc * CH + jo;
        float qv[G];
        #pragma unroll
        for (int g = 0; g < G; ++g) qv[g] = q[g * M + jo];
        float kv[PP];
        if (PP == 8) {
            float4 k0 = *(const float4*)&k[(size_t)j * AH + p0];
            float4 k1 = *(const float4*)&k[(size_t)j * AH + p0 + 4];
            kv[0]=k0.x; kv[1]=k0.y; kv[2]=k0.z; kv[3]=k0.w;
            kv[4]=k1.x; kv[5]=k1.y; kv[6]=k1.z; kv[7]=k1.w;
        } else {
            float2 k0 = *(const float2*)&k[(size_t)j * AH + p0];
            kv[0]=k0.x; if (PP > 1) kv[1]=k0.y;
        }
        #pragma unroll
        for (int g = 0; g < G; ++g)
            #pragma unroll
            for (int pp = 0; pp < PP; ++pp) acc[g][pp] += qv[g] * kv[pp];
    }

    #pragma unroll
    for (int g = 0; g < G; ++g)
        #pragma unroll
        for (int pp = 0; pp < PP; ++pp) {
            float v = acc[g][pp];
            #pragma unroll
            for (int off = 32; off; off >>= 1) v += __shfl_down(v, off, 64);
            if (jl == 0)
                Lpart[(size_t)(((b * A + a0 + g) * AH) + p0 + pp) * KS + kc] = v;
        }
}

// ---------------------------------------------------------------- softmax
__global__ __launch_bounds__(64) void softmax_kernel(
    const float* __restrict__ Lpart, float* __restrict__ attn,
    int AH, int KS)
{
    const int row = blockIdx.x;
    const int p = threadIdx.x;
    float s = 0.f;
    if (p < AH) {
        const size_t base = (size_t)(row * AH + p) * KS;
        for (int kc = 0; kc < KS; ++kc) s += Lpart[base + kc];
    }
    float m = (p < AH) ? s : -3.4e38f;
    #pragma unroll
    for (int off = 32; off; off >>= 1) m = fmaxf(m, __shfl_xor(m, off, 64));
    float e = (p < AH) ? __expf(s - m) : 0.f;
    float t = e;
    #pragma unroll
    for (int off = 32; off; off >>= 1) t += __shfl_xor(t, off, 64);
    if (p < AH) attn[(size_t)row * AH + p] = e / t;
}

// ---------------------------------------------------------------- apply
// Round-4 verified structure (89 us): register-tiled 4x4, b128 LDS reads,
// per-iter V staging with XOR swizzle.  In-place safe.
template<int CELL>
__global__ __launch_bounds__(256) void apply_kernel(
    const float* __restrict__ vbuf, const float* __restrict__ attn,
    const float* __restrict__ xsrc, float* __restrict__ xdst,
    const float* __restrict__ gp, int gidx)
{
    constexpr int A  = (CELL == 0) ? 16 : 64;
    constexpr int AH = A / 2;            // 8 / 32
    constexpr int PADA = AH + 4;         // attnA row stride (12 / 36)
    constexpr int ITERS = (CELL == 1) ? 4 : 2;

    __shared__ float attnA[A * PADA];
    __shared__ float vls[(CELL == 0) ? 4 : 64 * 32];   // 8KB swizzled (1/2)

    const int tid = threadIdx.x;
    const int b = blockIdx.z, c = blockIdx.y;

    // stage attnA [a][p] padded (attn buffer is a-major: [b*A+a][p])
    for (int idx = tid; idx < A * AH / 4; idx += 256) {
        int a = idx / (AH / 4), q = idx % (AH / 4);
        *(float4*)&attnA[a * PADA + q * 4] =
            *(const float4*)&attn[(size_t)b * A * AH + a * AH + q * 4];
    }

    const float g = gp[gidx];
    const float* xs = xsrc + (size_t)b * XBS + (size_t)c * 65536;
    float*       xd = xdst + (size_t)b * XBS + (size_t)c * 65536;
    const float* vb = vbuf + (size_t)b * 8388608;

    if (CELL == 0) {
        __syncthreads();
        const int i0 = blockIdx.x * 8;
        const int r0 = (tid & 63) * 4;          // rows = i_l*64 + j (4 same-i j's)
        const int il = r0 >> 6, j0 = r0 & 63;
        const int a0 = (tid >> 6) * 4;
        float4 aa[2][4];
        #pragma unroll
        for (int ch = 0; ch < 2; ++ch)
            #pragma unroll
            for (int at = 0; at < 4; ++at)
                aa[ch][at] = *(const float4*)&attnA[(a0 + at) * PADA + ch * 4];
        for (int ig = 0; ig < 2; ++ig) {
            const int i = i0 + ig * 4 + il;
            const float* vrow = vb + ((size_t)(c * 64 + i) * 64 + j0) * 8;
            float acc[4][4];
            #pragma unroll
            for (int rt = 0; rt < 4; ++rt)
                #pragma unroll
                for (int at = 0; at < 4; ++at) acc[rt][at] = 0.f;
            #pragma unroll
            for (int ch = 0; ch < 2; ++ch)
                #pragma unroll
                for (int rt = 0; rt < 4; ++rt) {
                    float4 vv = *(const float4*)&vrow[rt * 8 + ch * 4];
                    #pragma unroll
                    for (int at = 0; at < 4; ++at)
                        acc[rt][at] += vv.x * aa[ch][at].x + vv.y * aa[ch][at].y
                                     + vv.z * aa[ch][at].z + vv.w * aa[ch][at].w;
                }
            #pragma unroll
            for (int at = 0; at < 4; ++at) {
                int a = a0 + at;
                size_t xi = (size_t)a * 4096 + i * 64 + j0;
                float4 sv = *(const float4*)&xs[xi];
                *(float4*)&xd[xi] = make_float4(
                    g * acc[0][at] + sv.x, g * acc[1][at] + sv.y,
                    g * acc[2][at] + sv.z, g * acc[3][at] + sv.w);
            }
        }
    } else {
        const int k = tid & 15, r0 = k * 4;     // row-quad (j / i*16+j)
        const int a0 = (tid >> 4) * 4;
        for (int itn = 0; itn < ITERS; ++itn) {
            const int ib = (CELL == 1) ? (blockIdx.x * 4 + itn)
                                       : ((blockIdx.x * 2 + itn) * 4);
            __syncthreads();   // prior-iter LDS reads done (+attnA at itn=0)
            {  // stage 64 rows x 32 p, XOR-swizzled
                const int rowbase = c * 1024 + ib * ((CELL == 1) ? 64 : 16);
                const float* src = vb + (size_t)rowbase * 32;
                int rr = tid >> 3, cc = tid & 7;
                #pragma unroll
                for (int u = 0; u < 2; ++u) {
                    int r = rr + u * 32;
                    int slot = cc ^ ((r >> 2) & 7);
                    *(float4*)&vls[r * 32 + slot * 4] =
                        *(const float4*)&src[r * 32 + cc * 4];
                }
            }
            __syncthreads();
            float acc[4][4];
            #pragma unroll
            for (int rt = 0; rt < 4; ++rt)
                #pragma unroll
                for (int at = 0; at < 4; ++at) acc[rt][at] = 0.f;
            #pragma unroll
            for (int ch = 0; ch < 8; ++ch) {
                const int slot = (ch ^ (k & 7)) * 4;   // (r0>>2)&7 == k&7
                float4 aa[4];
                #pragma unroll
                for (int at = 0; at < 4; ++at)
                    aa[at] = *(const float4*)&attnA[(a0 + at) * PADA + ch * 4];
                #pragma unroll
                for (int rt = 0; rt < 4; ++rt) {
                    float4 vv = *(const float4*)&vls[(r0 + rt) * 32 + slot];
                    #pragma unroll
                    for (int at = 0; at < 4; ++at)
                        acc[rt][at] += vv.x * aa[at].x + vv.y * aa[at].y
                                     + vv.z * aa[at].z + vv.w * aa[at].w;
                }
            }
            if (CELL == 1) {
                const int i = ib, j0 = r0;
                #pragma unroll
                for (int at = 0; at < 4; ++at) {
                    int a = a0 + at;
                    size_t xi = (size_t)i * 4096 + a * 64 + j0;
                    float4 sv = *(const float4*)&xs[xi];
                    *(float4*)&xd[xi] = make_float4(
                        g * acc[0][at] + sv.x, g * acc[1][at] + sv.y,
                        g * acc[2][at] + sv.z, g * acc[3][at] + sv.w);
                }
            } else {
                #pragma unroll
                for (int rt = 0; rt < 4; ++rt) {
                    int r = r0 + rt;
                    int i = ib + (r >> 4), j = r & 15;
                    size_t xi = (size_t)i * 1024 + j * 64 + a0;
                    float4 sv = *(const float4*)&xs[xi];
                    *(float4*)&xd[xi] = make_float4(
                        g * acc[rt][0] + sv.x, g * acc[rt][1] + sv.y,
                        g * acc[rt][2] + sv.z, g * acc[rt][3] + sv.w);
                }
            }
        }
    }
}

// ---------------------------------------------------------------- launch
extern "C" void kernel_launch(void* const* d_in, const int* in_sizes, int n_in,
                              void* d_out, int out_size, void* d_ws, size_t ws_size,
                              hipStream_t stream)
{
    const float* x  = (const float*)d_in[0];
    const float* Wq = (const float*)d_in[1];
    const float* bq = (const float*)d_in[2];
    const float* Wk = (const float*)d_in[3];
    const float* bk = (const float*)d_in[4];
    const float* Wv = (const float*)d_in[5];
    const float* bv = (const float*)d_in[6];
    const float* gm = (const float*)d_in[7];
    float* out = (float*)d_out;

    float* ws   = (float*)d_ws;
    float* qbuf = ws;                      // 16777216 f
    float* kbuf = qbuf + 16777216;         //  8388608 f
    float* vbuf = kbuf + 8388608;          // 16777216 f
    float* Lp   = vbuf + 16777216;         //    65536 f
    float* attn = Lp + 65536;              //     4096 f
    unsigned int* wfb = (unsigned int*)(attn + 4096);   // 3*131072 u32 (1.5MiB)
    unsigned int* xTp = wfb + 3 * 131072;               // 33554432 u32 (128MiB)

    dim3 B256(256), B64(64);

    // weight prep (frag-ordered bf16 hi/lo) — data-independent, once up front
    for (int c = 0; c < 3; ++c) {
        unsigned int* wfc = wfb + c * 131072;
        prep_w<<<dim3(16,4,2),B64,0,stream>>>(Wq + c*32768, wfc);
        prep_w<<<dim3(16,4,2),B64,0,stream>>>(Wk + c*32768, wfc + 32768);
        prep_w<<<dim3(16,8,2),B64,0,stream>>>(Wv + c*65536, wfc + 65536);
    }

    // ---- cell 0: 'T' ----
    xsplit_kernel<0><<<dim3(1024,4,2),B256,0,stream>>>(x, xTp);
    mconv<false,12><<<dim3(512,1,2),B256,0,stream>>>(xTp, wfb,          bq, qbuf, 8388608);
    mconv<true ,12><<<dim3(512,1,2),B256,0,stream>>>(xTp, wfb + 32768,  bk, kbuf, 4194304);
    mconv_v<12><<<dim3(1024,1,2),B256,0,stream>>>(xTp, wfb + 65536,  bv, vbuf);
    logits_kernel<16,8,2,8,128,524288><<<dim3(128,2,2),B256,0,stream>>>(qbuf, kbuf, Lp);
    softmax_kernel<<<dim3(32),B64,0,stream>>>(Lp, attn, 8, 128);
    apply_kernel<0><<<dim3(8,256,2),B256,0,stream>>>(vbuf, attn, x, out, gm, 0);

    // ---- cell 1: 'W' ----
    unsigned int* wf1 = wfb + 131072;
    xsplit_kernel<1><<<dim3(1024,4,2),B256,0,stream>>>(out, xTp);
    mconv<false,10><<<dim3(512,1,2),B256,0,stream>>>(xTp, wf1,          bq+128, qbuf, 8388608);
    mconv<true ,10><<<dim3(512,1,2),B256,0,stream>>>(xTp, wf1 + 32768,  bk+128, kbuf, 4194304);
    mconv_v<10><<<dim3(1024,1,2),B256,0,stream>>>(xTp, wf1 + 65536,  bv+256, vbuf);
    logits_kernel<64,32,8,8,16,131072><<<dim3(16,8,2),B256,0,stream>>>(qbuf, kbuf, Lp);
    softmax_kernel<<<dim3(128),B64,0,stream>>>(Lp, attn, 32, 16);
    apply_kernel<1><<<dim3(4,256,2),B256,0,stream>>>(vbuf, attn, out, out, gm, 1);

    // ---- cell 2: 'H' ----
    unsigned int* wf2 = wfb + 262144;
    xsplit_kernel<2><<<dim3(1024,4,2),B256,0,stream>>>(out, xTp);
    mconv<false,10><<<dim3(512,1,2),B256,0,stream>>>(xTp, wf2,          bq+256, qbuf, 8388608);
    mconv<true ,10><<<dim3(512,1,2),B256,0,stream>>>(xTp, wf2 + 32768,  bk+256, kbuf, 4194304);
    mconv_v<10><<<dim3(1024,1,2),B256,0,stream>>>(xTp, wf2 + 65536,  bv+512, vbuf);
    logits_kernel<64,32,8,8,16,131072><<<dim3(16,8,2),B256,0,stream>>>(qbuf, kbuf, Lp);
    softmax_kernel<<<dim3(128),B64,0,stream>>>(Lp, attn, 32, 16);
    apply_kernel<2><<<dim3(8,256,2),B256,0,stream>>>(vbuf, attn, out, out, gm, 2);
}

// Round 7
// 1137.030 us; speedup vs baseline: 1.2164x; 1.0828x over previous
//
#include <hip/hip_runtime.h>

// SeparableAttn: B=2, C=256, T=16, W=64, H=64.  All fp32 in/out.
// Cells: 0='T' (A=16,S=4096), 1='W' (A=64,S=1024), 2='H' (A=64,S=1024).
// Convs on MFMA (bf16 3-term split).  Cells 0/1: convs read fp32 input
// DIRECTLY (fconv/fconv_v: gather+transpose+split in staging) -- xsplit
// eliminated for those cells (xTp added no traffic savings: 4B/elem either
// way).  Cell 2 keeps xsplit (its permute is genuinely strided).
// Applies register-tiled 4x4 fp32 (round-4 verified structure).
// ws: qbuf 64M + kbuf 32M + vbuf 64M + Lp/attn + wfrag 1.5M + xTp 128M ~ 304MiB.

constexpr int XBS = 16777216; // per-batch x floats (256*16*64*64)

typedef __attribute__((ext_vector_type(8)))  short short8v;   // 8 bf16 = 4 VGPR
typedef __attribute__((ext_vector_type(16))) float f32x16;    // MFMA 32x32 acc

__device__ __forceinline__ unsigned rne16(float f) {
    unsigned u = __float_as_uint(f);
    return (u + 0x7FFFu + ((u >> 16) & 1u)) >> 16;   // bf16 RNE (finite vals)
}

// ---------------------------------------------------------------- prep_w
__global__ __launch_bounds__(64) void prep_w(
    const float* __restrict__ W, unsigned int* __restrict__ dst)
{
    const int l = threadIdx.x;
    const int ks = blockIdx.x, mf = blockIdx.y, hl = blockIdx.z;
    const float* src = W + (mf * 32 + (l & 31)) * 256 + ks * 16 + ((l >> 5) << 3);
    unsigned pk[4];
    #pragma unroll
    for (int e = 0; e < 4; ++e) {
        float f0 = src[2 * e], f1 = src[2 * e + 1];
        unsigned b0, b1;
        if (hl == 0) {
            b0 = __float_as_uint(f0) >> 16;
            b1 = __float_as_uint(f1) >> 16;
        } else {
            unsigned h0 = __float_as_uint(f0) & 0xFFFF0000u;
            unsigned h1 = __float_as_uint(f1) & 0xFFFF0000u;
            b0 = rne16(f0 - __uint_as_float(h0));
            b1 = rne16(f1 - __uint_as_float(h1));
        }
        pk[e] = b0 | (b1 << 16);
    }
    size_t off = ((size_t)(mf * 16 + ks) * 2 + hl) * 256 + l * 4;
    *(uint4*)&dst[off] = make_uint4(pk[0], pk[1], pk[2], pk[3]);
}

// ---------------------------------------------------------------- xsplit
// (cell 2 only now)  xTp[b][n][c] packed = split(x_perm[c][n]).
template<int CELL>
__global__ __launch_bounds__(256) void xsplit_kernel(
    const float* __restrict__ src, unsigned int* __restrict__ xTp)
{
    __shared__ float T[64][66];   // [c][run], pad 66
    const int tid = threadIdx.x;
    const int b = blockIdx.z, cb = blockIdx.y, nb = blockIdx.x;
    const int runbase = (CELL == 0) ? nb * 64
                                    : ((nb & 15) * 4096 + ((nb >> 4) << 6));
    const float* sp = src + (size_t)b * XBS + (size_t)(cb * 64) * 65536 + runbase;
    #pragma unroll
    for (int i = 0; i < 4; ++i) {
        int id = tid + i * 256;
        int cl = id >> 4, rc = (id & 15) * 4;
        const float4 v = *(const float4*)&sp[(size_t)cl * 65536 + rc];
        *(float2*)&T[cl][rc]     = make_float2(v.x, v.y);
        *(float2*)&T[cl][rc + 2] = make_float2(v.z, v.w);
    }
    __syncthreads();
    unsigned int* dst = xTp + (size_t)b * (65536u * 256u);
    #pragma unroll
    for (int ps = 0; ps < 4; ++ps) {
        int r = ps * 16 + (tid >> 4);       // run index
        int c0 = (tid & 15) * 4;
        unsigned pk[4];
        #pragma unroll
        for (int e = 0; e < 4; ++e) {
            float f = T[c0 + e][r];
            unsigned hi = __float_as_uint(f) & 0xFFFF0000u;
            pk[e] = hi | rne16(f - __uint_as_float(hi));
        }
        int n_row = (CELL == 2) ? (r * 1024 + nb) : (nb * 64 + r);
        *(uint4*)&dst[(size_t)n_row * 256 + cb * 64 + c0] =
            make_uint4(pk[0], pk[1], pk[2], pk[3]);
    }
}

// ---------------------------------------------------------------- fconv
// Direct-fp32 MFMA conv for cells 0/1.  Staging: coalesced float4 gather
// (4c x 4n), register transpose, trunc/rne split, uint2 LDS writes.
// Thread map rq=(sb&7)|(((sb>>5)&3)<<3), cq=((sb>>3)&3)|(((sb>>7)&3)<<2):
// global runs of 8 quads (128B), LDS writes 4-way max (== mconv level).
// Offsets verified against the original scalar conv's off0/off1.
template<int CELL, bool POOL>
__global__ __launch_bounds__(256, 2) void fconv(
    const float* __restrict__ xf, const unsigned int* __restrict__ wf,
    const float* __restrict__ bias, float* __restrict__ out, int obs)
{
    constexpr int NS = POOL ? 32768 : 65536;
    constexpr int MF = POOL ? 2 : 4;
    constexpr int NV = POOL ? 2 : 1;

    __shared__ __align__(16) unsigned short Bh[128 * 64];
    __shared__ __align__(16) unsigned short Bl[128 * 64];

    const int tid = threadIdx.x;
    const int lane = tid & 63, wv = tid >> 6;
    const int b = blockIdx.z, gy = blockIdx.y, nb = blockIdx.x;
    const float* xb = xf + (size_t)b * XBS;

    f32x16 acc[MF][NV];
    #pragma unroll
    for (int m = 0; m < MF; ++m)
        #pragma unroll
        for (int v = 0; v < NV; ++v)
            #pragma unroll
            for (int r = 0; r < 16; ++r) acc[m][v][r] = 0.f;

    for (int ko = 0; ko < 4; ++ko) {
        const int c0 = ko * 64;
        #pragma unroll
        for (int s = 0; s < 2; ++s) {
            const int sb = tid + s * 256;
            const int rq = (sb & 7) | (((sb >> 5) & 3) << 3);     // [0,32)
            const int cq = ((sb >> 3) & 3) | (((sb >> 7) & 3) << 2); // [0,16)
            const int r4 = rq * 4;
            int off;
            if (!POOL) {
                int n = nb * 128 + r4;
                off = (CELL == 0) ? n
                    : ((n >> 6) & 15) * 4096 + ((n >> 10) << 6) + (n & 63);
            } else {
                int v = rq >> 4;
                int m = nb * 64 + (rq & 15) * 4;
                if (CELL == 0) off = ((2 * (m >> 12) + v) << 12) + (m & 4095);
                else off = (((m & 1023) >> 6) << 12) + ((2 * (m >> 10) + v) << 6) + (m & 63);
            }
            const float* src = xb + (size_t)(c0 + cq * 4) * 65536 + off;
            float4 f0 = *(const float4*)(src);
            float4 f1 = *(const float4*)(src + 65536);
            float4 f2 = *(const float4*)(src + 131072);
            float4 f3 = *(const float4*)(src + 196608);
            const float fr[4][4] = {{f0.x,f1.x,f2.x,f3.x},{f0.y,f1.y,f2.y,f3.y},
                                    {f0.z,f1.z,f2.z,f3.z},{f0.w,f1.w,f2.w,f3.w}};
            #pragma unroll
            for (int rn = 0; rn < 4; ++rn) {
                unsigned h[4], l[4];
                #pragma unroll
                for (int e = 0; e < 4; ++e) {
                    unsigned hi = __float_as_uint(fr[rn][e]) & 0xFFFF0000u;
                    h[e] = hi;
                    l[e] = rne16(fr[rn][e] - __uint_as_float(hi));
                }
                int row = r4 + rn;
                int byt = row * 128 + (((cq >> 1) ^ (row & 7)) << 4) + ((cq & 1) << 3);
                *(uint2*)((char*)Bh + byt) = make_uint2((h[0] >> 16) | h[1],
                                                        (h[2] >> 16) | h[3]);
                *(uint2*)((char*)Bl + byt) = make_uint2(l[0] | (l[1] << 16),
                                                        l[2] | (l[3] << 16));
            }
        }
        __syncthreads();
        #pragma unroll
        for (int ks = 0; ks < 4; ++ks) {
            short8v ah[MF], al[MF];
            #pragma unroll
            for (int m = 0; m < MF; ++m) {
                int mfG = gy * 4 + (POOL ? ((wv >> 1) * 2 + m) : m);
                const unsigned int* ap =
                    wf + (size_t)((mfG * 16 + ko * 4 + ks) * 2) * 256 + lane * 4;
                ah[m] = *(const short8v*)ap;
                al[m] = *(const short8v*)(ap + 256);
            }
            #pragma unroll
            for (int v = 0; v < NV; ++v) {
                int row = POOL ? (v * 64 + (wv & 1) * 32 + (lane & 31))
                               : (wv * 32 + (lane & 31));
                int byt = row * 128 + (((ks * 2 + (lane >> 5)) ^ (row & 7)) << 4);
                short8v bh = *(const short8v*)((char*)Bh + byt);
                short8v bl = *(const short8v*)((char*)Bl + byt);
                #pragma unroll
                for (int m = 0; m < MF; ++m) {
                    acc[m][v] = __builtin_amdgcn_mfma_f32_32x32x16_bf16(ah[m], bh, acc[m][v], 0, 0, 0);
                    acc[m][v] = __builtin_amdgcn_mfma_f32_32x32x16_bf16(ah[m], bl, acc[m][v], 0, 0, 0);
                    acc[m][v] = __builtin_amdgcn_mfma_f32_32x32x16_bf16(al[m], bh, acc[m][v], 0, 0, 0);
                }
            }
        }
        __syncthreads();
    }

    float* ob = out + (size_t)b * obs;
    const int colbase = POOL ? (nb * 64 + (wv & 1) * 32 + (lane & 31))
                             : (nb * 128 + wv * 32 + (lane & 31));
    #pragma unroll
    for (int m = 0; m < MF; ++m) {
        int mfG = gy * 4 + (POOL ? ((wv >> 1) * 2 + m) : m);
        #pragma unroll
        for (int r = 0; r < 16; ++r) {
            int o = mfG * 32 + (r & 3) + 8 * (r >> 2) + 4 * (lane >> 5);
            float val = POOL ? fmaxf(acc[m][0][r], acc[m][1][r]) : acc[m][0][r];
            ob[(size_t)o * NS + colbase] = val + bias[o];
        }
    }
}

// ---------------------------------------------------------------- fconv_v
// Direct-fp32 V conv for cells 0/1: 32 pooled cols x 256 o per block.
template<int CELL>
__global__ __launch_bounds__(256, 2) void fconv_v(
    const float* __restrict__ xf, const unsigned int* __restrict__ wf,
    const float* __restrict__ bias, float* __restrict__ out)
{
    __shared__ __align__(16) unsigned short Bh[64 * 64];
    __shared__ __align__(16) unsigned short Bl[64 * 64];

    const int tid = threadIdx.x;
    const int lane = tid & 63, wv = tid >> 6;
    const int b = blockIdx.z, nb = blockIdx.x;
    const float* xb = xf + (size_t)b * XBS;

    f32x16 acc[2][2];
    #pragma unroll
    for (int m = 0; m < 2; ++m)
        #pragma unroll
        for (int v = 0; v < 2; ++v)
            #pragma unroll
            for (int r = 0; r < 16; ++r) acc[m][v][r] = 0.f;

    for (int ko = 0; ko < 4; ++ko) {
        const int c0 = ko * 64;
        {
            const int sb = tid;                                   // 256 subblocks
            const int rq = (sb & 7) | (((sb >> 5) & 1) << 3);     // [0,16)
            const int cq = ((sb >> 3) & 3) | (((sb >> 6) & 3) << 2); // [0,16)
            const int r4 = rq * 4;
            const int v = rq >> 3;
            const int m = nb * 32 + (rq & 7) * 4;
            int off;
            if (CELL == 0) off = ((2 * (m >> 12) + v) << 12) + (m & 4095);
            else off = (((m & 1023) >> 6) << 12) + ((2 * (m >> 10) + v) << 6) + (m & 63);
            const float* src = xb + (size_t)(c0 + cq * 4) * 65536 + off;
            float4 f0 = *(const float4*)(src);
            float4 f1 = *(const float4*)(src + 65536);
            float4 f2 = *(const float4*)(src + 131072);
            float4 f3 = *(const float4*)(src + 196608);
            const float fr[4][4] = {{f0.x,f1.x,f2.x,f3.x},{f0.y,f1.y,f2.y,f3.y},
                                    {f0.z,f1.z,f2.z,f3.z},{f0.w,f1.w,f2.w,f3.w}};
            #pragma unroll
            for (int rn = 0; rn < 4; ++rn) {
                unsigned h[4], l[4];
                #pragma unroll
                for (int e = 0; e < 4; ++e) {
                    unsigned hi = __float_as_uint(fr[rn][e]) & 0xFFFF0000u;
                    h[e] = hi;
                    l[e] = rne16(fr[rn][e] - __uint_as_float(hi));
                }
                int row = r4 + rn;
                int byt = row * 128 + (((cq >> 1) ^ (row & 7)) << 4) + ((cq & 1) << 3);
                *(uint2*)((char*)Bh + byt) = make_uint2((h[0] >> 16) | h[1],
                                                        (h[2] >> 16) | h[3]);
                *(uint2*)((char*)Bl + byt) = make_uint2(l[0] | (l[1] << 16),
                                                        l[2] | (l[3] << 16));
            }
        }
        __syncthreads();
        #pragma unroll
        for (int ks = 0; ks < 4; ++ks) {
            short8v ah[2], al[2];
            #pragma unroll
            for (int m = 0; m < 2; ++m) {
                int mfG = wv * 2 + m;
                const unsigned int* ap =
                    wf + (size_t)((mfG * 16 + ko * 4 + ks) * 2) * 256 + lane * 4;
                ah[m] = *(const short8v*)ap;
                al[m] = *(const short8v*)(ap + 256);
            }
            #pragma unroll
            for (int v = 0; v < 2; ++v) {
                int row = v * 32 + (lane & 31);
                int byt = row * 128 + (((ks * 2 + (lane >> 5)) ^ (row & 7)) << 4);
                short8v bh = *(const short8v*)((char*)Bh + byt);
                short8v bl = *(const short8v*)((char*)Bl + byt);
                #pragma unroll
                for (int m = 0; m < 2; ++m) {
                    acc[m][v] = __builtin_amdgcn_mfma_f32_32x32x16_bf16(ah[m], bh, acc[m][v], 0, 0, 0);
                    acc[m][v] = __builtin_amdgcn_mfma_f32_32x32x16_bf16(ah[m], bl, acc[m][v], 0, 0, 0);
                    acc[m][v] = __builtin_amdgcn_mfma_f32_32x32x16_bf16(al[m], bh, acc[m][v], 0, 0, 0);
                }
            }
        }
        __syncthreads();
    }

    float* ob = out + (size_t)b * 8388608;
    const int colbase = nb * 32 + (lane & 31);
    #pragma unroll
    for (int m = 0; m < 2; ++m) {
        int mfG = wv * 2 + m;
        #pragma unroll
        for (int r = 0; r < 16; ++r) {
            int o = mfG * 32 + (r & 3) + 8 * (r >> 2) + 4 * (lane >> 5);
            float val = fmaxf(acc[m][0][r], acc[m][1][r]);
            ob[(size_t)o * 32768 + colbase] = val + bias[o];
        }
    }
}

// ---------------------------------------------------------------- mconv
// xTp-reading conv (cell 2 only now).
template<bool POOL, int LGS>
__global__ __launch_bounds__(256, 2) void mconv(
    const unsigned int* __restrict__ xTp, const unsigned int* __restrict__ wf,
    const float* __restrict__ bias, float* __restrict__ out, int obs)
{
    constexpr int NS = POOL ? 32768 : 65536;
    constexpr int MF = POOL ? 2 : 4;
    constexpr int NV = POOL ? 2 : 1;

    __shared__ __align__(16) unsigned short Bh[128 * 64];
    __shared__ __align__(16) unsigned short Bl[128 * 64];

    const int tid = threadIdx.x;
    const int lane = tid & 63, wv = tid >> 6;
    const int b = blockIdx.z, gy = blockIdx.y, nb = blockIdx.x;
    const unsigned int* xb = xTp + (size_t)b * (65536u * 256u);

    f32x16 acc[MF][NV];
    #pragma unroll
    for (int m = 0; m < MF; ++m)
        #pragma unroll
        for (int v = 0; v < NV; ++v)
            #pragma unroll
            for (int r = 0; r < 16; ++r) acc[m][v][r] = 0.f;

    for (int ko = 0; ko < 4; ++ko) {
        const int c0u = ko * 64;
        #pragma unroll
        for (int i = 0; i < 8; ++i) {
            int id = tid + i * 256;
            int row = id >> 4, q4 = id & 15;
            int n_src;
            if (!POOL) n_src = nb * 128 + row;
            else {
                int v = row >> 6, m = nb * 64 + (row & 63);
                int p = m >> LGS, s = m & ((1 << LGS) - 1);
                n_src = ((2 * p + v) << LGS) + s;
            }
            const uint4 g = *(const uint4*)&xb[(size_t)n_src * 256 + c0u + q4 * 4];
            unsigned h01 = (g.x >> 16)     | (g.y & 0xFFFF0000u);
            unsigned h23 = (g.z >> 16)     | (g.w & 0xFFFF0000u);
            unsigned l01 = (g.x & 0xFFFFu) | (g.y << 16);
            unsigned l23 = (g.z & 0xFFFFu) | (g.w << 16);
            int byt = row * 128 + (((q4 >> 1) ^ (row & 7)) << 4) + ((q4 & 1) << 3);
            *(uint2*)((char*)Bh + byt) = make_uint2(h01, h23);
            *(uint2*)((char*)Bl + byt) = make_uint2(l01, l23);
        }
        __syncthreads();
        #pragma unroll
        for (int ks = 0; ks < 4; ++ks) {
            short8v ah[MF], al[MF];
            #pragma unroll
            for (int m = 0; m < MF; ++m) {
                int mfG = gy * 4 + (POOL ? ((wv >> 1) * 2 + m) : m);
                const unsigned int* ap =
                    wf + (size_t)((mfG * 16 + ko * 4 + ks) * 2) * 256 + lane * 4;
                ah[m] = *(const short8v*)ap;
                al[m] = *(const short8v*)(ap + 256);
            }
            #pragma unroll
            for (int v = 0; v < NV; ++v) {
                int row = POOL ? (v * 64 + (wv & 1) * 32 + (lane & 31))
                               : (wv * 32 + (lane & 31));
                int byt = row * 128 + (((ks * 2 + (lane >> 5)) ^ (row & 7)) << 4);
                short8v bh = *(const short8v*)((char*)Bh + byt);
                short8v bl = *(const short8v*)((char*)Bl + byt);
                #pragma unroll
                for (int m = 0; m < MF; ++m) {
                    acc[m][v] = __builtin_amdgcn_mfma_f32_32x32x16_bf16(ah[m], bh, acc[m][v], 0, 0, 0);
                    acc[m][v] = __builtin_amdgcn_mfma_f32_32x32x16_bf16(ah[m], bl, acc[m][v], 0, 0, 0);
                    acc[m][v] = __builtin_amdgcn_mfma_f32_32x32x16_bf16(al[m], bh, acc[m][v], 0, 0, 0);
                }
            }
        }
        __syncthreads();
    }

    float* ob = out + (size_t)b * obs;
    const int colbase = POOL ? (nb * 64 + (wv & 1) * 32 + (lane & 31))
                             : (nb * 128 + wv * 32 + (lane & 31));
    #pragma unroll
    for (int m = 0; m < MF; ++m) {
        int mfG = gy * 4 + (POOL ? ((wv >> 1) * 2 + m) : m);
        #pragma unroll
        for (int r = 0; r < 16; ++r) {
            int o = mfG * 32 + (r & 3) + 8 * (r >> 2) + 4 * (lane >> 5);
            float val = POOL ? fmaxf(acc[m][0][r], acc[m][1][r]) : acc[m][0][r];
            ob[(size_t)o * NS + colbase] = val + bias[o];
        }
    }
}

// ---------------------------------------------------------------- mconv_v
// xTp-reading V conv (cell 2 only now).
template<int LGS>
__global__ __launch_bounds__(256, 2) void mconv_v(
    const unsigned int* __restrict__ xTp, const unsigned int* __restrict__ wf,
    const float* __restrict__ bias, float* __restrict__ out)
{
    __shared__ __align__(16) unsigned short Bh[64 * 64];
    __shared__ __align__(16) unsigned short Bl[64 * 64];

    const int tid = threadIdx.x;
    const int lane = tid & 63, wv = tid >> 6;
    const int b = blockIdx.z, nb = blockIdx.x;
    const unsigned int* xb = xTp + (size_t)b * (65536u * 256u);

    f32x16 acc[2][2];
    #pragma unroll
    for (int m = 0; m < 2; ++m)
        #pragma unroll
        for (int v = 0; v < 2; ++v)
            #pragma unroll
            for (int r = 0; r < 16; ++r) acc[m][v][r] = 0.f;

    for (int ko = 0; ko < 4; ++ko) {
        const int c0u = ko * 64;
        #pragma unroll
        for (int i = 0; i < 4; ++i) {
            int id = tid + i * 256;
            int row = id >> 4, q4 = id & 15;
            int v = row >> 5, m = nb * 32 + (row & 31);
            int p = m >> LGS, s = m & ((1 << LGS) - 1);
            int n_src = ((2 * p + v) << LGS) + s;
            const uint4 g = *(const uint4*)&xb[(size_t)n_src * 256 + c0u + q4 * 4];
            unsigned h01 = (g.x >> 16)     | (g.y & 0xFFFF0000u);
            unsigned h23 = (g.z >> 16)     | (g.w & 0xFFFF0000u);
            unsigned l01 = (g.x & 0xFFFFu) | (g.y << 16);
            unsigned l23 = (g.z & 0xFFFFu) | (g.w << 16);
            int byt = row * 128 + (((q4 >> 1) ^ (row & 7)) << 4) + ((q4 & 1) << 3);
            *(uint2*)((char*)Bh + byt) = make_uint2(h01, h23);
            *(uint2*)((char*)Bl + byt) = make_uint2(l01, l23);
        }
        __syncthreads();
        #pragma unroll
        for (int ks = 0; ks < 4; ++ks) {
            short8v ah[2], al[2];
            #pragma unroll
            for (int m = 0; m < 2; ++m) {
                int mfG = wv * 2 + m;
                const unsigned int* ap =
                    wf + (size_t)((mfG * 16 + ko * 4 + ks) * 2) * 256 + lane * 4;
                ah[m] = *(const short8v*)ap;
                al[m] = *(const short8v*)(ap + 256);
            }
            #pragma unroll
            for (int v = 0; v < 2; ++v) {
                int row = v * 32 + (lane & 31);
                int byt = row * 128 + (((ks * 2 + (lane >> 5)) ^ (row & 7)) << 4);
                short8v bh = *(const short8v*)((char*)Bh + byt);
                short8v bl = *(const short8v*)((char*)Bl + byt);
                #pragma unroll
                for (int m = 0; m < 2; ++m) {
                    acc[m][v] = __builtin_amdgcn_mfma_f32_32x32x16_bf16(ah[m], bh, acc[m][v], 0, 0, 0);
                    acc[m][v] = __builtin_amdgcn_mfma_f32_32x32x16_bf16(ah[m], bl, acc[m][v], 0, 0, 0);
                    acc[m][v] = __builtin_amdgcn_mfma_f32_32x32x16_bf16(al[m], bh, acc[m][v], 0, 0, 0);
                }
            }
        }
        __syncthreads();
    }

    float* ob = out + (size_t)b * 8388608;
    const int colbase = nb * 32 + (lane & 31);
    #pragma unroll
    for (int m = 0; m < 2; ++m) {
        int mfG = wv * 2 + m;
        #pragma unroll
        for (int r = 0; r < 16; ++r) {
            int o = mfG * 32 + (r & 3) + 8 * (r >> 2) + 4 * (lane >> 5);
            float val = fmaxf(acc[m][0][r], acc[m][1][r]);
            ob[(size_t)o * 32768 + colbase] = val + bias[o];
        }
    }
}

// ---------------------------------------------------------------- logits
template<int A, int AH, int PP, int G, int KS, int M>
__global__ __launch_bounds__(256) void logits_kernel(
    const float* __restrict__ qb, const float* __restrict__ kb,
    float* __restrict__ Lpart)
{
    const int tid = threadIdx.x;
    const int jl = tid & 63, pg = tid >> 6;
    const int p0 = pg * PP;
    const int b = blockIdx.z, a0 = blockIdx.y * G, kc = blockIdx.x;
    constexpr int CH = M / KS;
    const float* q = qb + (size_t)b * 8388608 + (size_t)a0 * M + (size_t)kc * CH;
    const float* k = kb + (size_t)b * 4194304;

    float acc[G][PP];
    #pragma unroll
    for (int g = 0; g < G; ++g)
        #pragma unroll
        for (int pp = 0; pp < PP; ++pp) acc[g][pp] = 0.f;

    for (int it = 0; it < CH / 64; ++it) {
        const int jo = jl + it * 64;
        const int j  = kc * CH + jo;
        float qv[G];
        #pragma unroll
        for (int g = 0; g < G; ++g) qv[g] = q[g * M + jo];
        float kv[PP];
        if (PP == 8) {
            float4 k0 = *(const float4*)&k[(size_t)j * AH + p0];
            float4 k1 = *(const float4*)&k[(size_t)j * AH + p0 + 4];
            kv[0]=k0.x; kv[1]=k0.y; kv[2]=k0.z; kv[3]=k0.w;
            kv[4]=k1.x; kv[5]=k1.y; kv[6]=k1.z; kv[7]=k1.w;
        } else {
            float2 k0 = *(const float2*)&k[(size_t)j * AH + p0];
            kv[0]=k0.x; if (PP > 1) kv[1]=k0.y;
        }
        #pragma unroll
        for (int g = 0; g < G; ++g)
            #pragma unroll
            for (int pp = 0; pp < PP; ++pp) acc[g][pp] += qv[g] * kv[pp];
    }

    #pragma unroll
    for (int g = 0; g < G; ++g)
        #pragma unroll
        for (int pp = 0; pp < PP; ++pp) {
            float v = acc[g][pp];
            #pragma unroll
            for (int off = 32; off; off >>= 1) v += __shfl_down(v, off, 64);
            if (jl == 0)
                Lpart[(size_t)(((b * A + a0 + g) * AH) + p0 + pp) * KS + kc] = v;
        }
}

// ---------------------------------------------------------------- softmax
__global__ __launch_bounds__(64) void softmax_kernel(
    const float* __restrict__ Lpart, float* __restrict__ attn,
    int AH, int KS)
{
    const int row = blockIdx.x;
    const int p = threadIdx.x;
    float s = 0.f;
    if (p < AH) {
        const size_t base = (size_t)(row * AH + p) * KS;
        for (int kc = 0; kc < KS; ++kc) s += Lpart[base + kc];
    }
    float m = (p < AH) ? s : -3.4e38f;
    #pragma unroll
    for (int off = 32; off; off >>= 1) m = fmaxf(m, __shfl_xor(m, off, 64));
    float e = (p < AH) ? __expf(s - m) : 0.f;
    float t = e;
    #pragma unroll
    for (int off = 32; off; off >>= 1) t += __shfl_xor(t, off, 64);
    if (p < AH) attn[(size_t)row * AH + p] = e / t;
}

// ---------------------------------------------------------------- apply
// Round-4 verified structure (89 us).  In-place safe.
template<int CELL>
__global__ __launch_bounds__(256) void apply_kernel(
    const float* __restrict__ vbuf, const float* __restrict__ attn,
    const float* __restrict__ xsrc, float* __restrict__ xdst,
    const float* __restrict__ gp, int gidx)
{
    constexpr int A  = (CELL == 0) ? 16 : 64;
    constexpr int AH = A / 2;            // 8 / 32
    constexpr int PADA = AH + 4;         // attnA row stride (12 / 36)
    constexpr int ITERS = (CELL == 1) ? 4 : 2;

    __shared__ float attnA[A * PADA];
    __shared__ float vls[(CELL == 0) ? 4 : 64 * 32];   // 8KB swizzled (1/2)

    const int tid = threadIdx.x;
    const int b = blockIdx.z, c = blockIdx.y;

    for (int idx = tid; idx < A * AH / 4; idx += 256) {
        int a = idx / (AH / 4), q = idx % (AH / 4);
        *(float4*)&attnA[a * PADA + q * 4] =
            *(const float4*)&attn[(size_t)b * A * AH + a * AH + q * 4];
    }

    const float g = gp[gidx];
    const float* xs = xsrc + (size_t)b * XBS + (size_t)c * 65536;
    float*       xd = xdst + (size_t)b * XBS + (size_t)c * 65536;
    const float* vb = vbuf + (size_t)b * 8388608;

    if (CELL == 0) {
        __syncthreads();
        const int i0 = blockIdx.x * 8;
        const int r0 = (tid & 63) * 4;
        const int il = r0 >> 6, j0 = r0 & 63;
        const int a0 = (tid >> 6) * 4;
        float4 aa[2][4];
        #pragma unroll
        for (int ch = 0; ch < 2; ++ch)
            #pragma unroll
            for (int at = 0; at < 4; ++at)
                aa[ch][at] = *(const float4*)&attnA[(a0 + at) * PADA + ch * 4];
        for (int ig = 0; ig < 2; ++ig) {
            const int i = i0 + ig * 4 + il;
            const float* vrow = vb + ((size_t)(c * 64 + i) * 64 + j0) * 8;
            float acc[4][4];
            #pragma unroll
            for (int rt = 0; rt < 4; ++rt)
                #pragma unroll
                for (int at = 0; at < 4; ++at) acc[rt][at] = 0.f;
            #pragma unroll
            for (int ch = 0; ch < 2; ++ch)
                #pragma unroll
                for (int rt = 0; rt < 4; ++rt) {
                    float4 vv = *(const float4*)&vrow[rt * 8 + ch * 4];
                    #pragma unroll
                    for (int at = 0; at < 4; ++at)
                        acc[rt][at] += vv.x * aa[ch][at].x + vv.y * aa[ch][at].y
                                     + vv.z * aa[ch][at].z + vv.w * aa[ch][at].w;
                }
            #pragma unroll
            for (int at = 0; at < 4; ++at) {
                int a = a0 + at;
                size_t xi = (size_t)a * 4096 + i * 64 + j0;
                float4 sv = *(const float4*)&xs[xi];
                *(float4*)&xd[xi] = make_float4(
                    g * acc[0][at] + sv.x, g * acc[1][at] + sv.y,
                    g * acc[2][at] + sv.z, g * acc[3][at] + sv.w);
            }
        }
    } else {
        const int k = tid & 15, r0 = k * 4;
        const int a0 = (tid >> 4) * 4;
        for (int itn = 0; itn < ITERS; ++itn) {
            const int ib = (CELL == 1) ? (blockIdx.x * 4 + itn)
                                       : ((blockIdx.x * 2 + itn) * 4);
            __syncthreads();
            {
                const int rowbase = c * 1024 + ib * ((CELL == 1) ? 64 : 16);
                const float* src = vb + (size_t)rowbase * 32;
                int rr = tid >> 3, cc = tid & 7;
                #pragma unroll
                for (int u = 0; u < 2; ++u) {
                    int r = rr + u * 32;
                    int slot = cc ^ ((r >> 2) & 7);
                    *(float4*)&vls[r * 32 + slot * 4] =
                        *(const float4*)&src[r * 32 + cc * 4];
                }
            }
            __syncthreads();
            float acc[4][4];
            #pragma unroll
            for (int rt = 0; rt < 4; ++rt)
                #pragma unroll
                for (int at = 0; at < 4; ++at) acc[rt][at] = 0.f;
            #pragma unroll
            for (int ch = 0; ch < 8; ++ch) {
                const int slot = (ch ^ (k & 7)) * 4;
                float4 aa[4];
                #pragma unroll
                for (int at = 0; at < 4; ++at)
                    aa[at] = *(const float4*)&attnA[(a0 + at) * PADA + ch * 4];
                #pragma unroll
                for (int rt = 0; rt < 4; ++rt) {
                    float4 vv = *(const float4*)&vls[(r0 + rt) * 32 + slot];
                    #pragma unroll
                    for (int at = 0; at < 4; ++at)
                        acc[rt][at] += vv.x * aa[at].x + vv.y * aa[at].y
                                     + vv.z * aa[at].z + vv.w * aa[at].w;
                }
            }
            if (CELL == 1) {
                const int i = ib, j0 = r0;
                #pragma unroll
                for (int at = 0; at < 4; ++at) {
                    int a = a0 + at;
                    size_t xi = (size_t)i * 4096 + a * 64 + j0;
                    float4 sv = *(const float4*)&xs[xi];
                    *(float4*)&xd[xi] = make_float4(
                        g * acc[0][at] + sv.x, g * acc[1][at] + sv.y,
                        g * acc[2][at] + sv.z, g * acc[3][at] + sv.w);
                }
            } else {
                #pragma unroll
                for (int rt = 0; rt < 4; ++rt) {
                    int r = r0 + rt;
                    int i = ib + (r >> 4), j = r & 15;
                    size_t xi = (size_t)i * 1024 + j * 64 + a0;
                    float4 sv = *(const float4*)&xs[xi];
                    *(float4*)&xd[xi] = make_float4(
                        g * acc[rt][0] + sv.x, g * acc[rt][1] + sv.y,
                        g * acc[rt][2] + sv.z, g * acc[rt][3] + sv.w);
                }
            }
        }
    }
}

// ---------------------------------------------------------------- launch
extern "C" void kernel_launch(void* const* d_in, const int* in_sizes, int n_in,
                              void* d_out, int out_size, void* d_ws, size_t ws_size,
                              hipStream_t stream)
{
    const float* x  = (const float*)d_in[0];
    const float* Wq = (const float*)d_in[1];
    const float* bq = (const float*)d_in[2];
    const float* Wk = (const float*)d_in[3];
    const float* bk = (const float*)d_in[4];
    const float* Wv = (const float*)d_in[5];
    const float* bv = (const float*)d_in[6];
    const float* gm = (const float*)d_in[7];
    float* out = (float*)d_out;

    float* ws   = (float*)d_ws;
    float* qbuf = ws;                      // 16777216 f
    float* kbuf = qbuf + 16777216;         //  8388608 f
    float* vbuf = kbuf + 8388608;          // 16777216 f
    float* Lp   = vbuf + 16777216;         //    65536 f
    float* attn = Lp + 65536;              //     4096 f
    unsigned int* wfb = (unsigned int*)(attn + 4096);   // 3*131072 u32 (1.5MiB)
    unsigned int* xTp = wfb + 3 * 131072;               // 33554432 u32 (128MiB)

    dim3 B256(256), B64(64);

    // weight prep (frag-ordered bf16 hi/lo) — data-independent, once up front
    for (int c = 0; c < 3; ++c) {
        unsigned int* wfc = wfb + c * 131072;
        prep_w<<<dim3(16,4,2),B64,0,stream>>>(Wq + c*32768, wfc);
        prep_w<<<dim3(16,4,2),B64,0,stream>>>(Wk + c*32768, wfc + 32768);
        prep_w<<<dim3(16,8,2),B64,0,stream>>>(Wv + c*65536, wfc + 65536);
    }

    // ---- cell 0: 'T' (direct-fp32 convs; no xsplit) ----
    fconv<0,false><<<dim3(512,1,2),B256,0,stream>>>(x, wfb,          bq, qbuf, 8388608);
    fconv<0,true ><<<dim3(512,1,2),B256,0,stream>>>(x, wfb + 32768,  bk, kbuf, 4194304);
    fconv_v<0><<<dim3(1024,1,2),B256,0,stream>>>(x, wfb + 65536,  bv, vbuf);
    logits_kernel<16,8,2,8,128,524288><<<dim3(128,2,2),B256,0,stream>>>(qbuf, kbuf, Lp);
    softmax_kernel<<<dim3(32),B64,0,stream>>>(Lp, attn, 8, 128);
    apply_kernel<0><<<dim3(8,256,2),B256,0,stream>>>(vbuf, attn, x, out, gm, 0);

    // ---- cell 1: 'W' (direct-fp32 convs; no xsplit) ----
    unsigned int* wf1 = wfb + 131072;
    fconv<1,false><<<dim3(512,1,2),B256,0,stream>>>(out, wf1,          bq+128, qbuf, 8388608);
    fconv<1,true ><<<dim3(512,1,2),B256,0,stream>>>(out, wf1 + 32768,  bk+128, kbuf, 4194304);
    fconv_v<1><<<dim3(1024,1,2),B256,0,stream>>>(out, wf1 + 65536,  bv+256, vbuf);
    logits_kernel<64,32,8,8,16,131072><<<dim3(16,8,2),B256,0,stream>>>(qbuf, kbuf, Lp);
    softmax_kernel<<<dim3(128),B64,0,stream>>>(Lp, attn, 32, 16);
    apply_kernel<1><<<dim3(4,256,2),B256,0,stream>>>(vbuf, attn, out, out, gm, 1);

    // ---- cell 2: 'H' (strided permute -> keep xsplit + xTp convs) ----
    unsigned int* wf2 = wfb + 262144;
    xsplit_kernel<2><<<dim3(1024,4,2),B256,0,stream>>>(out, xTp);
    mconv<false,10><<<dim3(512,1,2),B256,0,stream>>>(xTp, wf2,          bq+256, qbuf, 8388608);
    mconv<true ,10><<<dim3(512,1,2),B256,0,stream>>>(xTp, wf2 + 32768,  bk+256, kbuf, 4194304);
    mconv_v<10><<<dim3(1024,1,2),B256,0,stream>>>(xTp, wf2 + 65536,  bv+512, vbuf);
    logits_kernel<64,32,8,8,16,131072><<<dim3(16,8,2),B256,0,stream>>>(qbuf, kbuf, Lp);
    softmax_kernel<<<dim3(128),B64,0,stream>>>(Lp, attn, 32, 16);
    apply_kernel<2><<<dim3(8,256,2),B256,0,stream>>>(vbuf, attn, out, out, gm, 2);
}